// Round 1
// 216.513 us; speedup vs baseline: 1.0097x; 1.0097x over previous
//
#include <hip/hip_runtime.h>
#include <hip/hip_bf16.h>
#include <stdint.h>

// B=2, T=2048, D=1024, H=16, hd=64.
// R6: attn with sigma-permuted PV -- P stays in registers (the PV mfma's k-dim
// is re-ordered so each lane's S^T output IS its PV B-operand); V fragment
// read with matching sigma addressing (2x ds_read_b64). P LDS eliminated:
// LDS 64KB->32KB, no P bank conflicts, no store->load wait in the tile loop.

typedef unsigned short u16;
typedef short bf16x8 __attribute__((ext_vector_type(8)));
typedef float f32x4  __attribute__((ext_vector_type(4)));

#if defined(__has_builtin) && __has_builtin(__builtin_amdgcn_exp2f)
#define EXP2F(x) __builtin_amdgcn_exp2f(x)
#else
#define EXP2F(x) exp2f(x)
#endif

__device__ __forceinline__ u16 f2b(float f) {           // fp32 -> bf16 RNE
  uint32_t u = __float_as_uint(f);
  u += 0x7fffu + ((u >> 16) & 1u);
  return (u16)(u >> 16);
}
__device__ __forceinline__ uint32_t pk2(float a, float b) {
  return (uint32_t)f2b(a) | ((uint32_t)f2b(b) << 16);
}
__device__ __forceinline__ uint32_t pkbf(float a, float b) {  // v_cvt_pk_bf16_f32
  __hip_bfloat162 h = __float22bfloat162_rn(make_float2(a, b));
  union { __hip_bfloat162 h2; uint32_t u; } cv; cv.h2 = h;
  return cv.u;
}

// async global->LDS DMA, 16B per lane. LDS dest must be uniform-base + lane*16.
__device__ __forceinline__ void gl2lds16(const void* g, void* l) {
  __builtin_amdgcn_global_load_lds(
      (const __attribute__((address_space(1))) unsigned int*)g,
      (__attribute__((address_space(3))) unsigned int*)l, 16, 0, 0);
}

// ---------------------------------------------------------------- dtype sniff
__global__ void sniff_kernel(const u16* x, int* flag) {
  __shared__ int cnt;
  if (threadIdx.x == 0) cnt = 0;
  __syncthreads();
  int c = 0;
  for (int i = threadIdx.x; i < 4096; i += 256) {
    float a = fabsf(__uint_as_float(((uint32_t)x[2*i]) << 16));
    if (a > 1e-3f && a < 100.f) c++;
  }
  atomicAdd(&cnt, c);
  __syncthreads();
  if (threadIdx.x == 0) *flag = (cnt > 2048) ? 1 : 0;
}

// ------------------------------------------------- 64x64 transpose helper
__device__ __forceinline__ void tr_tile(const void* src, u16* dst, int Kd, int N,
                                        int n0, int k0, int isb, u16* Lt, int tid)
{
  const int r = tid >> 2, cseg = (tid & 3) << 4;
  u16 t[16];
  if (isb) {
    const u16* s = (const u16*)src + (size_t)(k0 + r) * N + n0 + cseg;
    *(uint4*)&t[0] = *(const uint4*)s;
    *(uint4*)&t[8] = *(const uint4*)(s + 8);
  } else {
    const float* s = (const float*)src + (size_t)(k0 + r) * N + n0 + cseg;
    #pragma unroll
    for (int j = 0; j < 4; j++) {
      float4 v = *(const float4*)(s + j * 4);
      t[j*4+0] = f2b(v.x); t[j*4+1] = f2b(v.y); t[j*4+2] = f2b(v.z); t[j*4+3] = f2b(v.w);
    }
  }
  #pragma unroll
  for (int j = 0; j < 16; j++) Lt[(cseg + j) * 72 + r] = t[j];
  __syncthreads();
  const int n = tid >> 2, kseg = (tid & 3) << 4;
  uint4 u0 = *(const uint4*)&Lt[n * 72 + kseg];
  uint4 u1 = *(const uint4*)&Lt[n * 72 + kseg + 8];
  u16* d = dst + (size_t)(n0 + n) * Kd + k0 + kseg;
  *(uint4*)d = u0;
  *(uint4*)(d + 8) = u1;
}

// ------------------------------------------------- fused prep
// blocks [0,2048): x->bf16 ; [2048,2816): Wqkv^T ; [2816,3072): Wout^T ;
// [3072,3328): RoPE table CS[t*32+f] = {cos,sin}
__global__ __launch_bounds__(256) void prep_kernel(
    const void* __restrict__ x, const void* __restrict__ wqkv,
    const void* __restrict__ wout, const int* __restrict__ flag,
    u16* __restrict__ Xb, u16* __restrict__ Wqkvt, u16* __restrict__ Woutt,
    float2* __restrict__ CS)
{
  __shared__ u16 Lt[64 * 72];
  const int isb = *flag;
  const int bid = blockIdx.x, tid = threadIdx.x;
  if (bid < 2048) {
    const size_t i = ((size_t)bid * 256 + tid) * 8;
    if (isb) {
      *(uint4*)&Xb[i] = *(const uint4*)((const u16*)x + i);
    } else {
      const float* s = (const float*)x + i;
      float4 a = *(const float4*)s, b = *(const float4*)(s + 4);
      uint4 p;
      p.x = pkbf(a.x, a.y); p.y = pkbf(a.z, a.w);
      p.z = pkbf(b.x, b.y); p.w = pkbf(b.z, b.w);
      *(uint4*)&Xb[i] = p;
    }
  } else if (bid < 2816) {
    const int b = bid - 2048;
    tr_tile(wqkv, Wqkvt, 1024, 3072, (b % 48) * 64, (b / 48) * 64, isb, Lt, tid);
  } else if (bid < 3072) {
    const int b = bid - 2816;
    tr_tile(wout, Woutt, 1024, 1024, (b % 16) * 64, (b / 16) * 64, isb, Lt, tid);
  } else {
    const int idx = (bid - 3072) * 256 + tid;   // 65536
    const int t = idx >> 5, f = idx & 31;
    float invf = __expf(-(float)f * 0.2878231366242557f);  // ln(1e4)/32
    float th = (float)t * invf;
    float sn, cs;
    sincosf(th, &sn, &cs);
    CS[idx] = make_float2(cs, sn);
  }
}

// ------------------------------------------------- QKV GEMM (NT, bf16) + RoPE
__global__ __launch_bounds__(256) void qkv_kernel(
    const u16* __restrict__ Xb, const u16* __restrict__ Wt,
    const float2* __restrict__ CS,
    u16* __restrict__ Q, u16* __restrict__ K, u16* __restrict__ Vt)
{
  __shared__ u16 As[128 * 64];
  __shared__ u16 Bs[128 * 64];
  const int tid = threadIdx.x;
  const int n0 = blockIdx.x * 128;
  const int m0 = blockIdx.y * 128;
  const int w = tid >> 6, l = tid & 63, lr = l & 15, lq = l >> 4;
  const int mrow0 = (w & 1) * 64;
  const int ncol0 = (w >> 1) * 64;
  const int srow = tid >> 3;
  const int gseg = (tid & 7) ^ (srow & 7);

  f32x4 acc[4][4] = {};

  for (int k0 = 0; k0 < 1024; k0 += 64) {
    __syncthreads();
    #pragma unroll
    for (int rd = 0; rd < 4; rd++) {
      const int row = srow + rd * 32;
      gl2lds16(Xb + (size_t)(m0 + row) * 1024 + k0 + gseg * 8, &As[tid * 8 + rd * 2048]);
      gl2lds16(Wt + (size_t)(n0 + row) * 1024 + k0 + gseg * 8, &Bs[tid * 8 + rd * 2048]);
    }
    __syncthreads();
    #pragma unroll
    for (int kc = 0; kc < 2; kc++) {
      bf16x8 af[4], bf[4];
      #pragma unroll
      for (int i = 0; i < 4; i++) {
        const int seg = ((kc << 2) | lq) ^ (lr & 7);
        af[i] = *(const bf16x8*)&As[(mrow0 + i * 16 + lr) * 64 + seg * 8];
        bf[i] = *(const bf16x8*)&Bs[(ncol0 + i * 16 + lr) * 64 + seg * 8];
      }
      #pragma unroll
      for (int mb = 0; mb < 4; mb++)
        #pragma unroll
        for (int nb = 0; nb < 4; nb++)
          acc[mb][nb] = __builtin_amdgcn_mfma_f32_16x16x32_bf16(af[mb], bf[nb], acc[mb][nb], 0, 0, 0);
    }
  }

  const int col0 = n0 + ncol0;
  const int sec = col0 >> 10;            // 0=q 1=k 2=v
  const int h = (col0 >> 6) & 15;
  if (sec == 2) {
    #pragma unroll
    for (int mb = 0; mb < 4; mb++) {
      const int row0 = m0 + mrow0 + mb * 16 + lq * 4;
      const int b = row0 >> 11, t0 = row0 & 2047;
      #pragma unroll
      for (int nb = 0; nb < 4; nb++) {
        const int d = nb * 16 + lr;
        uint2 uv;
        uv.x = pkbf(acc[mb][nb][0], acc[mb][nb][1]);
        uv.y = pkbf(acc[mb][nb][2], acc[mb][nb][3]);
        *(uint2*)&Vt[(((size_t)b * 16 + h) * 64 + d) * 2048 + t0] = uv;
      }
    }
  } else {
    u16* dst = (sec == 0) ? Q : K;
    const float qscale = 0.125f * 1.44269504f;   // 1/sqrt(hd) * log2(e), q only
    #pragma unroll
    for (int mb = 0; mb < 4; mb++) {
      const int row0 = m0 + mrow0 + mb * 16 + lq * 4;
      const int b = row0 >> 11, t0 = row0 & 2047;
      #pragma unroll
      for (int nb = 0; nb < 4; nb++) {
        const int d = nb * 16 + lr;
        const int f = d & 31;
        #pragma unroll
        for (int r = 0; r < 4; r++) {
          const int t = t0 + r;
          float2 cs = CS[t * 32 + f];
          float val = acc[mb][nb][r];
          float prt = __shfl_xor(val, 1, 64);   // partner col d^1 = lane lr^1
          float res = fmaf(val, cs.x, ((d & 1) ? prt : -prt) * cs.y);
          if (sec == 0) res *= qscale;
          dst[(((size_t)b * 16 + h) * 2048 + t) * 64 + d] = f2b(res);
        }
      }
    }
  }
}

// ------------------------------------------------- MFMA flash attention (R6)
// Block = 4 waves x 64 q-rows = 256 rows of one (b,h). gridDim.y = ns s-splits.
// S^T = mfma(Kfrag, Qfrag): lane (m=l&15, quad lq) holds s = sb*16+lq*4+{0..3}.
// PV k-dim permutation sigma(k = q*8+j) = (j>>2)*16 + q*4 + (j&3) makes the
// lane's own packed exp values the PV B-operand (pf0={sb0,sb1}, pf1={sb2,sb3});
// V fragment read with matching sigma addressing (2x ds_read_b64 per frag).
// No P LDS at all. Double-buffered K/V DMA, one barrier per 64-s tile.
__global__ __launch_bounds__(256, 2) void attn_kernel(
    const u16* __restrict__ Q, const u16* __restrict__ K,
    const u16* __restrict__ Vt, u16* __restrict__ ATT,
    float* __restrict__ Op, float* __restrict__ Ls)
{
  __shared__ u16 Ks[2][64 * 64];    // 16 KB
  __shared__ u16 Vs[2][64 * 64];    // 16 KB
  const int tid = threadIdx.x;
  const int w = tid >> 6, l = tid & 63, lr = l & 15, lq = l >> 4;
  const int bh = blockIdx.x >> 3;
  const int qt = blockIdx.x & 7;
  const int ns = gridDim.y, sh = blockIdx.y;
  const int slen = 2048 / ns;
  const int sbeg = sh * slen;
  const size_t base = (size_t)bh * (2048 * 64);
  const int qrow0 = qt * 256 + w * 64;

  // Q fragments (used as B-operand: col m = lane&15, k = quad*8+j)
  bf16x8 qf[4][2];
  #pragma unroll
  for (int mb = 0; mb < 4; mb++)
    #pragma unroll
    for (int kc = 0; kc < 2; kc++)
      qf[mb][kc] = *(const bf16x8*)(Q + base + (size_t)(qrow0 + mb * 16 + lr) * 64 + kc * 32 + lq * 8);

  f32x4 oa[4][4] = {};            // O^T: [db][mb]
  float lsum[4] = {0.f, 0.f, 0.f, 0.f};

  const int srow = tid >> 3;

  auto stage = [&](int buf, int s0) {
    #pragma unroll
    for (int rd = 0; rd < 2; rd++) {
      const int row = srow + rd * 32;
      const int gs = (tid & 7) ^ (row & 7);
      gl2lds16(K + base + (size_t)(s0 + row) * 64 + gs * 8, &Ks[buf][tid * 8 + rd * 2048]);
      gl2lds16(Vt + base + (size_t)row * 2048 + s0 + gs * 8, &Vs[buf][tid * 8 + rd * 2048]);
    }
  };

  stage(0, sbeg);
  const int nt = slen >> 6;

  #pragma unroll 1
  for (int t = 0; t < nt; t++) {
    const int buf = t & 1;
    __syncthreads();                       // drains DMA for buf, fences prev reads
    if (t + 1 < nt) stage(buf ^ 1, sbeg + (t + 1) * 64);

    // K fragments: A-operand, row s = nb*16 + (l&15), k(d) = kc*32+lq*8+j.
    // V fragments: A-operand, row d = nb*16 + (l&15), k = sigma-ordered s.
    bf16x8 kf[4][2], vf[4][2];
    #pragma unroll
    for (int nb = 0; nb < 4; nb++)
      #pragma unroll
      for (int kc = 0; kc < 2; kc++) {
        const int seg = ((kc << 2) | lq) ^ (lr & 7);
        kf[nb][kc] = *(const bf16x8*)&Ks[buf][(nb * 16 + lr) * 64 + seg * 8];
        // sigma V read: j=0..3 from t-off kc*32+lq*4, j=4..7 from kc*32+16+lq*4
        const int sa = ((kc << 2) | (lq >> 1)) ^ (lr & 7);
        const int sb2 = ((kc << 2) | 2 | (lq >> 1)) ^ (lr & 7);
        const int hh = (lq & 1) * 4;
        union { uint2 p[2]; bf16x8 v; } uv;
        uv.p[0] = *(const uint2*)&Vs[buf][(nb * 16 + lr) * 64 + sa * 8 + hh];
        uv.p[1] = *(const uint2*)&Vs[buf][(nb * 16 + lr) * 64 + sb2 * 8 + hh];
        vf[nb][kc] = uv.v;
      }

    // Per m-block: S^T (rows s, col m) -> exp -> pack in-lane -> PV.
    #pragma unroll
    for (int mb = 0; mb < 4; mb++) {
      uint32_t pw[8];
      #pragma unroll
      for (int sb = 0; sb < 4; sb++) {
        f32x4 st = {};
        st = __builtin_amdgcn_mfma_f32_16x16x32_bf16(kf[sb][0], qf[mb][0], st, 0, 0, 0);
        st = __builtin_amdgcn_mfma_f32_16x16x32_bf16(kf[sb][1], qf[mb][1], st, 0, 0, 0);
        float e0 = EXP2F(st[0]), e1 = EXP2F(st[1]), e2 = EXP2F(st[2]), e3 = EXP2F(st[3]);
        lsum[mb] += (e0 + e1) + (e2 + e3);
        pw[2 * sb]     = pkbf(e0, e1);
        pw[2 * sb + 1] = pkbf(e2, e3);
      }
      union { uint32_t u[4]; bf16x8 v; } p0, p1;
      p0.u[0] = pw[0]; p0.u[1] = pw[1]; p0.u[2] = pw[2]; p0.u[3] = pw[3];
      p1.u[0] = pw[4]; p1.u[1] = pw[5]; p1.u[2] = pw[6]; p1.u[3] = pw[7];
      #pragma unroll
      for (int db = 0; db < 4; db++) {
        oa[db][mb] = __builtin_amdgcn_mfma_f32_16x16x32_bf16(vf[db][0], p0.v, oa[db][mb], 0, 0, 0);
        oa[db][mb] = __builtin_amdgcn_mfma_f32_16x16x32_bf16(vf[db][1], p1.v, oa[db][mb], 0, 0, 0);
      }
    }
  }

  // reduce row sums across quads (lanes lr, lr+16, lr+32, lr+48)
  #pragma unroll
  for (int mb = 0; mb < 4; mb++) {
    float v = lsum[mb];
    v += __shfl_xor(v, 16, 64);
    v += __shfl_xor(v, 32, 64);
    lsum[mb] = v;
  }

  const int b = bh >> 4, h = bh & 15;
  if (ns == 1) {
    #pragma unroll
    for (int mb = 0; mb < 4; mb++) {
      const float inv = 1.f / lsum[mb];
      const int t = qrow0 + mb * 16 + lr;
      u16* dst = ATT + ((size_t)(b * 2048 + t)) * 1024 + h * 64;
      #pragma unroll
      for (int db = 0; db < 4; db++) {
        uint2 u;
        u.x = pkbf(oa[db][mb][0] * inv, oa[db][mb][1] * inv);
        u.y = pkbf(oa[db][mb][2] * inv, oa[db][mb][3] * inv);
        *(uint2*)&dst[db * 16 + lq * 4] = u;
      }
    }
  } else {
    float* op = Op + (size_t)sh * (65536ull * 64);
    #pragma unroll
    for (int mb = 0; mb < 4; mb++) {
      const size_t row = (size_t)bh * 2048 + qrow0 + mb * 16 + lr;
      #pragma unroll
      for (int db = 0; db < 4; db++)
        *(f32x4*)&op[row * 64 + db * 16 + lq * 4] = oa[db][mb];
      if (lq == 0) Ls[(size_t)sh * 65536 + row] = lsum[mb];
    }
  }
}

// ------------------------------------------------- combine s-split partials
__global__ __launch_bounds__(256) void combine_kernel(
    const float* __restrict__ Op, const float* __restrict__ Ls, u16* __restrict__ ATT)
{
  const int idx = blockIdx.x * 256 + threadIdx.x;   // 524288
  const int R = idx >> 3;
  const int c = (idx & 7) * 8;
  const float* p0 = Op + (size_t)R * 64 + c;
  const float* p1 = p0 + 65536ull * 64;
  f32x4 a0 = *(const f32x4*)p0, a1 = *(const f32x4*)(p0 + 4);
  f32x4 b0 = *(const f32x4*)p1, b1 = *(const f32x4*)(p1 + 4);
  const float inv = 1.f / (Ls[R] + Ls[65536 + R]);
  const int bh = R >> 11, trow = R & 2047;
  const int b = bh >> 4, h = bh & 15;
  u16* d = ATT + ((size_t)(b * 2048 + trow)) * 1024 + h * 64 + c;
  uint4 u;
  u.x = pkbf((a0[0] + b0[0]) * inv, (a0[1] + b0[1]) * inv);
  u.y = pkbf((a0[2] + b0[2]) * inv, (a0[3] + b0[3]) * inv);
  u.z = pkbf((a1[0] + b1[0]) * inv, (a1[1] + b1[1]) * inv);
  u.w = pkbf((a1[2] + b1[2]) * inv, (a1[3] + b1[3]) * inv);
  *(uint4*)d = u;
}

// ------------------------------------------------- output projection (NT, bf16)
__global__ __launch_bounds__(256) void outproj_kernel(
    const u16* __restrict__ A, const u16* __restrict__ Wt,
    const int* __restrict__ flag, void* __restrict__ outv)
{
  __shared__ u16 As[128 * 64];
  __shared__ u16 Bs[128 * 64];
  const int isb = *flag;
  const int tid = threadIdx.x;
  const int n0 = blockIdx.x * 128;
  const int m0 = blockIdx.y * 128;
  const int w = tid >> 6, l = tid & 63, lr = l & 15, lq = l >> 4;
  const int mrow0 = (w & 1) * 64;
  const int ncol0 = (w >> 1) * 64;
  const int srow = tid >> 3;
  const int gseg = (tid & 7) ^ (srow & 7);

  f32x4 acc[4][4] = {};

  for (int k0 = 0; k0 < 1024; k0 += 64) {
    __syncthreads();
    #pragma unroll
    for (int rd = 0; rd < 4; rd++) {
      const int row = srow + rd * 32;
      gl2lds16(A + (size_t)(m0 + row) * 1024 + k0 + gseg * 8, &As[tid * 8 + rd * 2048]);
      gl2lds16(Wt + (size_t)(n0 + row) * 1024 + k0 + gseg * 8, &Bs[tid * 8 + rd * 2048]);
    }
    __syncthreads();
    #pragma unroll
    for (int kc = 0; kc < 2; kc++) {
      bf16x8 af[4], bf[4];
      #pragma unroll
      for (int i = 0; i < 4; i++) {
        const int seg = ((kc << 2) | lq) ^ (lr & 7);
        af[i] = *(const bf16x8*)&As[(mrow0 + i * 16 + lr) * 64 + seg * 8];
        bf[i] = *(const bf16x8*)&Bs[(ncol0 + i * 16 + lr) * 64 + seg * 8];
      }
      #pragma unroll
      for (int mb = 0; mb < 4; mb++)
        #pragma unroll
        for (int nb = 0; nb < 4; nb++)
          acc[mb][nb] = __builtin_amdgcn_mfma_f32_16x16x32_bf16(af[mb], bf[nb], acc[mb][nb], 0, 0, 0);
    }
  }
  #pragma unroll
  for (int mb = 0; mb < 4; mb++) {
    const int row = m0 + mrow0 + mb * 16 + lq * 4;
    #pragma unroll
    for (int nb = 0; nb < 4; nb++) {
      const int col = n0 + ncol0 + nb * 16 + lr;
      #pragma unroll
      for (int r = 0; r < 4; r++) {
        float val = acc[mb][nb][r];
        if (isb) ((u16*)outv)[(size_t)(row + r) * 1024 + col] = f2b(val);
        else     ((float*)outv)[(size_t)(row + r) * 1024 + col] = val;
      }
    }
  }
}

extern "C" void kernel_launch(void* const* d_in, const int* in_sizes, int n_in,
                              void* d_out, int out_size, void* d_ws, size_t ws_size,
                              hipStream_t stream)
{
  const void* x    = d_in[0];
  const void* wqkv = d_in[1];
  const void* wout = d_in[2];
  char* ws = (char*)d_ws;
  const size_t MB = 1024 * 1024;
  int*    flag   = (int*)ws;
  float2* CS     = (float2*)(ws + 1024);            // 512 KB
  u16*    Xb     = (u16*)(ws + 1 * MB);             // 8 MB  (aliased by ATT)
  u16*    ATT    = Xb;
  u16*    Wqkvt  = (u16*)(ws + 9 * MB);             // 6 MB
  u16*    Woutt  = (u16*)(ws + 15 * MB);            // 2 MB
  u16*    Q      = (u16*)(ws + 17 * MB);            // 8 MB
  u16*    K      = (u16*)(ws + 25 * MB);            // 8 MB
  u16*    Vt     = (u16*)(ws + 33 * MB);            // 8 MB
  float*  Op     = (float*)(ws + 41 * MB);          // 32 MB (ns=2)
  float*  Ls     = (float*)(ws + 75 * MB);          // 0.5 MB

  const bool split = ws_size >= 76 * MB;            // deterministic across calls
  const int ns = split ? 2 : 1;

  sniff_kernel<<<1, 256, 0, stream>>>((const u16*)x, flag);
  prep_kernel<<<3328, 256, 0, stream>>>(x, wqkv, wout, flag, Xb, Wqkvt, Woutt, CS);
  qkv_kernel<<<dim3(24, 32), 256, 0, stream>>>(Xb, Wqkvt, CS, Q, K, Vt);
  attn_kernel<<<dim3(256, ns), 256, 0, stream>>>(Q, K, Vt, ATT, Op, Ls);
  if (split)
    combine_kernel<<<2048, 256, 0, stream>>>(Op, Ls, ATT);
  outproj_kernel<<<dim3(8, 32), 256, 0, stream>>>(ATT, Woutt, flag, d_out);
}

// Round 2
// 214.983 us; speedup vs baseline: 1.0169x; 1.0071x over previous
//
#include <hip/hip_runtime.h>
#include <hip/hip_bf16.h>
#include <stdint.h>

// B=2, T=2048, D=1024, H=16, hd=64.
// R7: attn occupancy 2x -- 32 q-rows/wave (qt=16), grid 1024 blocks = 4
// blocks/CU (16 waves/CU); XCD-bijective block swizzle (4 bh per XCD L2);
// V stored sigma-permuted in qkv so PV's V fragment is one conflict-free
// ds_read_b128 (same seg formula as K); setprio(1) around MFMA clusters.
// Tile body phased (S-phase then PV-phase) to keep VGPR under the 4-wave cap.

typedef unsigned short u16;
typedef short bf16x8 __attribute__((ext_vector_type(8)));
typedef float f32x4  __attribute__((ext_vector_type(4)));

#if defined(__has_builtin) && __has_builtin(__builtin_amdgcn_exp2f)
#define EXP2F(x) __builtin_amdgcn_exp2f(x)
#else
#define EXP2F(x) exp2f(x)
#endif

__device__ __forceinline__ u16 f2b(float f) {           // fp32 -> bf16 RNE
  uint32_t u = __float_as_uint(f);
  u += 0x7fffu + ((u >> 16) & 1u);
  return (u16)(u >> 16);
}
__device__ __forceinline__ uint32_t pkbf(float a, float b) {  // v_cvt_pk_bf16_f32
  __hip_bfloat162 h = __float22bfloat162_rn(make_float2(a, b));
  union { __hip_bfloat162 h2; uint32_t u; } cv; cv.h2 = h;
  return cv.u;
}

// async global->LDS DMA, 16B per lane. LDS dest must be uniform-base + lane*16.
__device__ __forceinline__ void gl2lds16(const void* g, void* l) {
  __builtin_amdgcn_global_load_lds(
      (const __attribute__((address_space(1))) unsigned int*)g,
      (__attribute__((address_space(3))) unsigned int*)l, 16, 0, 0);
}

// ---------------------------------------------------------------- dtype sniff
__global__ void sniff_kernel(const u16* x, int* flag) {
  __shared__ int cnt;
  if (threadIdx.x == 0) cnt = 0;
  __syncthreads();
  int c = 0;
  for (int i = threadIdx.x; i < 4096; i += 256) {
    float a = fabsf(__uint_as_float(((uint32_t)x[2*i]) << 16));
    if (a > 1e-3f && a < 100.f) c++;
  }
  atomicAdd(&cnt, c);
  __syncthreads();
  if (threadIdx.x == 0) *flag = (cnt > 2048) ? 1 : 0;
}

// ------------------------------------------------- 64x64 transpose helper
__device__ __forceinline__ void tr_tile(const void* src, u16* dst, int Kd, int N,
                                        int n0, int k0, int isb, u16* Lt, int tid)
{
  const int r = tid >> 2, cseg = (tid & 3) << 4;
  u16 t[16];
  if (isb) {
    const u16* s = (const u16*)src + (size_t)(k0 + r) * N + n0 + cseg;
    *(uint4*)&t[0] = *(const uint4*)s;
    *(uint4*)&t[8] = *(const uint4*)(s + 8);
  } else {
    const float* s = (const float*)src + (size_t)(k0 + r) * N + n0 + cseg;
    #pragma unroll
    for (int j = 0; j < 4; j++) {
      float4 v = *(const float4*)(s + j * 4);
      t[j*4+0] = f2b(v.x); t[j*4+1] = f2b(v.y); t[j*4+2] = f2b(v.z); t[j*4+3] = f2b(v.w);
    }
  }
  #pragma unroll
  for (int j = 0; j < 16; j++) Lt[(cseg + j) * 72 + r] = t[j];
  __syncthreads();
  const int n = tid >> 2, kseg = (tid & 3) << 4;
  uint4 u0 = *(const uint4*)&Lt[n * 72 + kseg];
  uint4 u1 = *(const uint4*)&Lt[n * 72 + kseg + 8];
  u16* d = dst + (size_t)(n0 + n) * Kd + k0 + kseg;
  *(uint4*)d = u0;
  *(uint4*)(d + 8) = u1;
}

// ------------------------------------------------- fused prep
// blocks [0,2048): x->bf16 ; [2048,2816): Wqkv^T ; [2816,3072): Wout^T ;
// [3072,3328): RoPE table CS[t*32+f] = {cos,sin}
__global__ __launch_bounds__(256) void prep_kernel(
    const void* __restrict__ x, const void* __restrict__ wqkv,
    const void* __restrict__ wout, const int* __restrict__ flag,
    u16* __restrict__ Xb, u16* __restrict__ Wqkvt, u16* __restrict__ Woutt,
    float2* __restrict__ CS)
{
  __shared__ u16 Lt[64 * 72];
  const int isb = *flag;
  const int bid = blockIdx.x, tid = threadIdx.x;
  if (bid < 2048) {
    const size_t i = ((size_t)bid * 256 + tid) * 8;
    if (isb) {
      *(uint4*)&Xb[i] = *(const uint4*)((const u16*)x + i);
    } else {
      const float* s = (const float*)x + i;
      float4 a = *(const float4*)s, b = *(const float4*)(s + 4);
      uint4 p;
      p.x = pkbf(a.x, a.y); p.y = pkbf(a.z, a.w);
      p.z = pkbf(b.x, b.y); p.w = pkbf(b.z, b.w);
      *(uint4*)&Xb[i] = p;
    }
  } else if (bid < 2816) {
    const int b = bid - 2048;
    tr_tile(wqkv, Wqkvt, 1024, 3072, (b % 48) * 64, (b / 48) * 64, isb, Lt, tid);
  } else if (bid < 3072) {
    const int b = bid - 2816;
    tr_tile(wout, Woutt, 1024, 1024, (b % 16) * 64, (b / 16) * 64, isb, Lt, tid);
  } else {
    const int idx = (bid - 3072) * 256 + tid;   // 65536
    const int t = idx >> 5, f = idx & 31;
    float invf = __expf(-(float)f * 0.2878231366242557f);  // ln(1e4)/32
    float th = (float)t * invf;
    float sn, cs;
    sincosf(th, &sn, &cs);
    CS[idx] = make_float2(cs, sn);
  }
}

// ------------------------------------------------- QKV GEMM (NT, bf16) + RoPE
// V is written with t pre-permuted by sigma (within each 32-t block:
// t = a*16 + q*4 + r  ->  k = q*8 + a*4 + r) so attn's PV B-operand is the
// lane's own S^T output and the V fragment is a plain b128 seg read.
__global__ __launch_bounds__(256) void qkv_kernel(
    const u16* __restrict__ Xb, const u16* __restrict__ Wt,
    const float2* __restrict__ CS,
    u16* __restrict__ Q, u16* __restrict__ K, u16* __restrict__ Vt)
{
  __shared__ u16 As[128 * 64];
  __shared__ u16 Bs[128 * 64];
  const int tid = threadIdx.x;
  const int n0 = blockIdx.x * 128;
  const int m0 = blockIdx.y * 128;
  const int w = tid >> 6, l = tid & 63, lr = l & 15, lq = l >> 4;
  const int mrow0 = (w & 1) * 64;
  const int ncol0 = (w >> 1) * 64;
  const int srow = tid >> 3;
  const int gseg = (tid & 7) ^ (srow & 7);

  f32x4 acc[4][4] = {};

  for (int k0 = 0; k0 < 1024; k0 += 64) {
    __syncthreads();
    #pragma unroll
    for (int rd = 0; rd < 4; rd++) {
      const int row = srow + rd * 32;
      gl2lds16(Xb + (size_t)(m0 + row) * 1024 + k0 + gseg * 8, &As[tid * 8 + rd * 2048]);
      gl2lds16(Wt + (size_t)(n0 + row) * 1024 + k0 + gseg * 8, &Bs[tid * 8 + rd * 2048]);
    }
    __syncthreads();
    #pragma unroll
    for (int kc = 0; kc < 2; kc++) {
      bf16x8 af[4], bf[4];
      #pragma unroll
      for (int i = 0; i < 4; i++) {
        const int seg = ((kc << 2) | lq) ^ (lr & 7);
        af[i] = *(const bf16x8*)&As[(mrow0 + i * 16 + lr) * 64 + seg * 8];
        bf[i] = *(const bf16x8*)&Bs[(ncol0 + i * 16 + lr) * 64 + seg * 8];
      }
      #pragma unroll
      for (int mb = 0; mb < 4; mb++)
        #pragma unroll
        for (int nb = 0; nb < 4; nb++)
          acc[mb][nb] = __builtin_amdgcn_mfma_f32_16x16x32_bf16(af[mb], bf[nb], acc[mb][nb], 0, 0, 0);
    }
  }

  const int col0 = n0 + ncol0;
  const int sec = col0 >> 10;            // 0=q 1=k 2=v
  const int h = (col0 >> 6) & 15;
  if (sec == 2) {
    #pragma unroll
    for (int mb = 0; mb < 4; mb++) {
      const int row0 = m0 + mrow0 + mb * 16 + lq * 4;
      const int b = row0 >> 11, t0 = row0 & 2047;
      // sigma permute within the 32-t block (t0 is a multiple of 4):
      const int tp = (t0 & ~31) | (((t0 >> 2) & 3) << 3) | (((t0 >> 4) & 1) << 2);
      #pragma unroll
      for (int nb = 0; nb < 4; nb++) {
        const int d = nb * 16 + lr;
        uint2 uv;
        uv.x = pkbf(acc[mb][nb][0], acc[mb][nb][1]);
        uv.y = pkbf(acc[mb][nb][2], acc[mb][nb][3]);
        *(uint2*)&Vt[(((size_t)b * 16 + h) * 64 + d) * 2048 + tp] = uv;
      }
    }
  } else {
    u16* dst = (sec == 0) ? Q : K;
    const float qscale = 0.125f * 1.44269504f;   // 1/sqrt(hd) * log2(e), q only
    #pragma unroll
    for (int mb = 0; mb < 4; mb++) {
      const int row0 = m0 + mrow0 + mb * 16 + lq * 4;
      const int b = row0 >> 11, t0 = row0 & 2047;
      #pragma unroll
      for (int nb = 0; nb < 4; nb++) {
        const int d = nb * 16 + lr;
        const int f = d & 31;
        #pragma unroll
        for (int r = 0; r < 4; r++) {
          const int t = t0 + r;
          float2 cs = CS[t * 32 + f];
          float val = acc[mb][nb][r];
          float prt = __shfl_xor(val, 1, 64);   // partner col d^1 = lane lr^1
          float res = fmaf(val, cs.x, ((d & 1) ? prt : -prt) * cs.y);
          if (sec == 0) res *= qscale;
          dst[(((size_t)b * 16 + h) * 2048 + t) * 64 + d] = f2b(res);
        }
      }
    }
  }
}

// ------------------------------------------------- MFMA flash attention (R7)
// Block = 4 waves x 32 q-rows = 128 rows of one (b,h). grid = 512*ns blocks
// (1D, XCD-bijective swizzle: each XCD owns 4 contiguous bh). Per tile:
// S^T = mfma(Kfrag, Qfrag) -> exp -> in-lane pack (PV k-dim sigma matches the
// sigma-permuted Vt store) -> PV with plain b128 V fragments. Phased body
// (kf and vf never co-live) to fit 4 waves/SIMD.
__global__ __launch_bounds__(256, 4) void attn_kernel(
    const u16* __restrict__ Q, const u16* __restrict__ K,
    const u16* __restrict__ Vt, u16* __restrict__ ATT,
    float* __restrict__ Op, float* __restrict__ Ls, int ns)
{
  __shared__ u16 Ks[2][64 * 64];    // 16 KB
  __shared__ u16 Vs[2][64 * 64];    // 16 KB
  const int tid = threadIdx.x;
  const int w = tid >> 6, l = tid & 63, lr = l & 15, lq = l >> 4;

  // XCD-bijective swizzle: hw block bid runs on XCD bid%8; give each XCD a
  // contiguous chunk of work ids so one XCD sees few distinct (b,h).
  const int nwg = 512 * ns;
  const int bid = blockIdx.x;
  const int swz = (bid & 7) * (nwg >> 3) + (bid >> 3);
  const int per_bh = 16 * ns;
  const int bh = swz / per_bh;
  const int rem = swz - bh * per_bh;
  const int sh = rem & (ns - 1);
  const int qt = rem / ns;

  const int slen = 2048 / ns;
  const int sbeg = sh * slen;
  const size_t base = (size_t)bh * (2048 * 64);
  const int qrow0 = qt * 128 + w * 32;

  // Q fragments (B-operand: col m = lane&15, k = quad*8+j)
  bf16x8 qf[2][2];
  #pragma unroll
  for (int mb = 0; mb < 2; mb++)
    #pragma unroll
    for (int kc = 0; kc < 2; kc++)
      qf[mb][kc] = *(const bf16x8*)(Q + base + (size_t)(qrow0 + mb * 16 + lr) * 64 + kc * 32 + lq * 8);

  f32x4 oa[4][2] = {};            // O^T: [db][mb]
  float lsum[2] = {0.f, 0.f};

  const int srow = tid >> 3;

  auto stage = [&](int buf, int s0) {
    #pragma unroll
    for (int rd = 0; rd < 2; rd++) {
      const int row = srow + rd * 32;
      const int gs = (tid & 7) ^ (row & 7);
      gl2lds16(K + base + (size_t)(s0 + row) * 64 + gs * 8, &Ks[buf][tid * 8 + rd * 2048]);
      gl2lds16(Vt + base + (size_t)row * 2048 + s0 + gs * 8, &Vs[buf][tid * 8 + rd * 2048]);
    }
  };

  stage(0, sbeg);
  const int nt = slen >> 6;

  #pragma unroll 1
  for (int t = 0; t < nt; t++) {
    const int buf = t & 1;
    __syncthreads();                       // drains DMA for buf, fences prev reads
    if (t + 1 < nt) stage(buf ^ 1, sbeg + (t + 1) * 64);

    // ---- S phase: K fragments (A-operand, row s = sb*16+lr, k = kc*32+lq*8+j)
    bf16x8 kf[4][2];
    #pragma unroll
    for (int sb = 0; sb < 4; sb++)
      #pragma unroll
      for (int kc = 0; kc < 2; kc++) {
        const int seg = ((kc << 2) | lq) ^ (lr & 7);
        kf[sb][kc] = *(const bf16x8*)&Ks[buf][(sb * 16 + lr) * 64 + seg * 8];
      }

    uint32_t pw[2][8];
    #pragma unroll
    for (int mb = 0; mb < 2; mb++) {
      f32x4 st[4];
      __builtin_amdgcn_s_setprio(1);
      #pragma unroll
      for (int sb = 0; sb < 4; sb++) {
        f32x4 z = {};
        z = __builtin_amdgcn_mfma_f32_16x16x32_bf16(kf[sb][0], qf[mb][0], z, 0, 0, 0);
        st[sb] = __builtin_amdgcn_mfma_f32_16x16x32_bf16(kf[sb][1], qf[mb][1], z, 0, 0, 0);
      }
      __builtin_amdgcn_s_setprio(0);
      #pragma unroll
      for (int sb = 0; sb < 4; sb++) {
        float e0 = EXP2F(st[sb][0]), e1 = EXP2F(st[sb][1]);
        float e2 = EXP2F(st[sb][2]), e3 = EXP2F(st[sb][3]);
        lsum[mb] += (e0 + e1) + (e2 + e3);
        pw[mb][2 * sb]     = pkbf(e0, e1);
        pw[mb][2 * sb + 1] = pkbf(e2, e3);
      }
    }

    // ---- PV phase: V fragments (A-operand, row d = db*16+lr, sigma-linear k)
    bf16x8 vf[4][2];
    #pragma unroll
    for (int db = 0; db < 4; db++)
      #pragma unroll
      for (int kc = 0; kc < 2; kc++) {
        const int seg = ((kc << 2) | lq) ^ (lr & 7);
        vf[db][kc] = *(const bf16x8*)&Vs[buf][(db * 16 + lr) * 64 + seg * 8];
      }

    __builtin_amdgcn_s_setprio(1);
    #pragma unroll
    for (int mb = 0; mb < 2; mb++) {
      union { uint32_t u[4]; bf16x8 v; } p0, p1;
      p0.u[0] = pw[mb][0]; p0.u[1] = pw[mb][1]; p0.u[2] = pw[mb][2]; p0.u[3] = pw[mb][3];
      p1.u[0] = pw[mb][4]; p1.u[1] = pw[mb][5]; p1.u[2] = pw[mb][6]; p1.u[3] = pw[mb][7];
      #pragma unroll
      for (int db = 0; db < 4; db++) {
        oa[db][mb] = __builtin_amdgcn_mfma_f32_16x16x32_bf16(vf[db][0], p0.v, oa[db][mb], 0, 0, 0);
        oa[db][mb] = __builtin_amdgcn_mfma_f32_16x16x32_bf16(vf[db][1], p1.v, oa[db][mb], 0, 0, 0);
      }
    }
    __builtin_amdgcn_s_setprio(0);
  }

  // reduce row sums across quads (lanes lr, lr+16, lr+32, lr+48)
  #pragma unroll
  for (int mb = 0; mb < 2; mb++) {
    float v = lsum[mb];
    v += __shfl_xor(v, 16, 64);
    v += __shfl_xor(v, 32, 64);
    lsum[mb] = v;
  }

  const int b = bh >> 4, h = bh & 15;
  if (ns == 1) {
    #pragma unroll
    for (int mb = 0; mb < 2; mb++) {
      const float inv = 1.f / lsum[mb];
      const int t = qrow0 + mb * 16 + lr;
      u16* dst = ATT + ((size_t)(b * 2048 + t)) * 1024 + h * 64;
      #pragma unroll
      for (int db = 0; db < 4; db++) {
        uint2 u;
        u.x = pkbf(oa[db][mb][0] * inv, oa[db][mb][1] * inv);
        u.y = pkbf(oa[db][mb][2] * inv, oa[db][mb][3] * inv);
        *(uint2*)&dst[db * 16 + lq * 4] = u;
      }
    }
  } else {
    float* op = Op + (size_t)sh * (65536ull * 64);
    #pragma unroll
    for (int mb = 0; mb < 2; mb++) {
      const size_t row = (size_t)bh * 2048 + qrow0 + mb * 16 + lr;
      #pragma unroll
      for (int db = 0; db < 4; db++)
        *(f32x4*)&op[row * 64 + db * 16 + lq * 4] = oa[db][mb];
      if (lq == 0) Ls[(size_t)sh * 65536 + row] = lsum[mb];
    }
  }
}

// ------------------------------------------------- combine s-split partials
__global__ __launch_bounds__(256) void combine_kernel(
    const float* __restrict__ Op, const float* __restrict__ Ls, u16* __restrict__ ATT)
{
  const int idx = blockIdx.x * 256 + threadIdx.x;   // 524288
  const int R = idx >> 3;
  const int c = (idx & 7) * 8;
  const float* p0 = Op + (size_t)R * 64 + c;
  const float* p1 = p0 + 65536ull * 64;
  f32x4 a0 = *(const f32x4*)p0, a1 = *(const f32x4*)(p0 + 4);
  f32x4 b0 = *(const f32x4*)p1, b1 = *(const f32x4*)(p1 + 4);
  const float inv = 1.f / (Ls[R] + Ls[65536 + R]);
  const int bh = R >> 11, trow = R & 2047;
  const int b = bh >> 4, h = bh & 15;
  u16* d = ATT + ((size_t)(b * 2048 + trow)) * 1024 + h * 64 + c;
  uint4 u;
  u.x = pkbf((a0[0] + b0[0]) * inv, (a0[1] + b0[1]) * inv);
  u.y = pkbf((a0[2] + b0[2]) * inv, (a0[3] + b0[3]) * inv);
  u.z = pkbf((a1[0] + b1[0]) * inv, (a1[1] + b1[1]) * inv);
  u.w = pkbf((a1[2] + b1[2]) * inv, (a1[3] + b1[3]) * inv);
  *(uint4*)d = u;
}

// ------------------------------------------------- output projection (NT, bf16)
__global__ __launch_bounds__(256) void outproj_kernel(
    const u16* __restrict__ A, const u16* __restrict__ Wt,
    const int* __restrict__ flag, void* __restrict__ outv)
{
  __shared__ u16 As[128 * 64];
  __shared__ u16 Bs[128 * 64];
  const int isb = *flag;
  const int tid = threadIdx.x;
  const int n0 = blockIdx.x * 128;
  const int m0 = blockIdx.y * 128;
  const int w = tid >> 6, l = tid & 63, lr = l & 15, lq = l >> 4;
  const int mrow0 = (w & 1) * 64;
  const int ncol0 = (w >> 1) * 64;
  const int srow = tid >> 3;
  const int gseg = (tid & 7) ^ (srow & 7);

  f32x4 acc[4][4] = {};

  for (int k0 = 0; k0 < 1024; k0 += 64) {
    __syncthreads();
    #pragma unroll
    for (int rd = 0; rd < 4; rd++) {
      const int row = srow + rd * 32;
      gl2lds16(A + (size_t)(m0 + row) * 1024 + k0 + gseg * 8, &As[tid * 8 + rd * 2048]);
      gl2lds16(Wt + (size_t)(n0 + row) * 1024 + k0 + gseg * 8, &Bs[tid * 8 + rd * 2048]);
    }
    __syncthreads();
    #pragma unroll
    for (int kc = 0; kc < 2; kc++) {
      bf16x8 af[4], bf[4];
      #pragma unroll
      for (int i = 0; i < 4; i++) {
        const int seg = ((kc << 2) | lq) ^ (lr & 7);
        af[i] = *(const bf16x8*)&As[(mrow0 + i * 16 + lr) * 64 + seg * 8];
        bf[i] = *(const bf16x8*)&Bs[(ncol0 + i * 16 + lr) * 64 + seg * 8];
      }
      #pragma unroll
      for (int mb = 0; mb < 4; mb++)
        #pragma unroll
        for (int nb = 0; nb < 4; nb++)
          acc[mb][nb] = __builtin_amdgcn_mfma_f32_16x16x32_bf16(af[mb], bf[nb], acc[mb][nb], 0, 0, 0);
    }
  }
  #pragma unroll
  for (int mb = 0; mb < 4; mb++) {
    const int row = m0 + mrow0 + mb * 16 + lq * 4;
    #pragma unroll
    for (int nb = 0; nb < 4; nb++) {
      const int col = n0 + ncol0 + nb * 16 + lr;
      #pragma unroll
      for (int r = 0; r < 4; r++) {
        float val = acc[mb][nb][r];
        if (isb) ((u16*)outv)[(size_t)(row + r) * 1024 + col] = f2b(val);
        else     ((float*)outv)[(size_t)(row + r) * 1024 + col] = val;
      }
    }
  }
}

extern "C" void kernel_launch(void* const* d_in, const int* in_sizes, int n_in,
                              void* d_out, int out_size, void* d_ws, size_t ws_size,
                              hipStream_t stream)
{
  const void* x    = d_in[0];
  const void* wqkv = d_in[1];
  const void* wout = d_in[2];
  char* ws = (char*)d_ws;
  const size_t MB = 1024 * 1024;
  int*    flag   = (int*)ws;
  float2* CS     = (float2*)(ws + 1024);            // 512 KB
  u16*    Xb     = (u16*)(ws + 1 * MB);             // 8 MB  (aliased by ATT)
  u16*    ATT    = Xb;
  u16*    Wqkvt  = (u16*)(ws + 9 * MB);             // 6 MB
  u16*    Woutt  = (u16*)(ws + 15 * MB);            // 2 MB
  u16*    Q      = (u16*)(ws + 17 * MB);            // 8 MB
  u16*    K      = (u16*)(ws + 25 * MB);            // 8 MB
  u16*    Vt     = (u16*)(ws + 33 * MB);            // 8 MB
  float*  Op     = (float*)(ws + 41 * MB);          // 32 MB (ns=2)
  float*  Ls     = (float*)(ws + 75 * MB);          // 0.5 MB

  const bool split = ws_size >= 76 * MB;            // deterministic across calls
  const int ns = split ? 2 : 1;

  sniff_kernel<<<1, 256, 0, stream>>>((const u16*)x, flag);
  prep_kernel<<<3328, 256, 0, stream>>>(x, wqkv, wout, flag, Xb, Wqkvt, Woutt, CS);
  qkv_kernel<<<dim3(24, 32), 256, 0, stream>>>(Xb, Wqkvt, CS, Q, K, Vt);
  attn_kernel<<<dim3(512 * ns), 256, 0, stream>>>(Q, K, Vt, ATT, Op, Ls, ns);
  if (split)
    combine_kernel<<<2048, 256, 0, stream>>>(Op, Ls, ATT);
  outproj_kernel<<<dim3(8, 32), 256, 0, stream>>>(ATT, Woutt, flag, d_out);
}

// Round 3
// 208.772 us; speedup vs baseline: 1.0472x; 1.0298x over previous
//
#include <hip/hip_runtime.h>
#include <hip/hip_bf16.h>
#include <stdint.h>

// B=2, T=2048, D=1024, H=16, hd=64.
// R8: qkv/outproj epilogue via transposed accumulators -- for Q/K/outproj the
// mfma operands are swapped (mfma(bf,af), same trick as attn's S^T) so each
// lane holds 4 CONSECUTIVE output columns: RoPE pairs are in-lane (0 shfl),
// CS loads are float4, stores are packed uint2/f32x4 (16 vs 64 per thread).
// V keeps original orientation (needs t-quad for the transposed sigma store).
// attn unchanged from R7 (control).

typedef unsigned short u16;
typedef short bf16x8 __attribute__((ext_vector_type(8)));
typedef float f32x4  __attribute__((ext_vector_type(4)));

#if defined(__has_builtin) && __has_builtin(__builtin_amdgcn_exp2f)
#define EXP2F(x) __builtin_amdgcn_exp2f(x)
#else
#define EXP2F(x) exp2f(x)
#endif

__device__ __forceinline__ u16 f2b(float f) {           // fp32 -> bf16 RNE
  uint32_t u = __float_as_uint(f);
  u += 0x7fffu + ((u >> 16) & 1u);
  return (u16)(u >> 16);
}
__device__ __forceinline__ uint32_t pkbf(float a, float b) {  // v_cvt_pk_bf16_f32
  __hip_bfloat162 h = __float22bfloat162_rn(make_float2(a, b));
  union { __hip_bfloat162 h2; uint32_t u; } cv; cv.h2 = h;
  return cv.u;
}

// async global->LDS DMA, 16B per lane. LDS dest must be uniform-base + lane*16.
__device__ __forceinline__ void gl2lds16(const void* g, void* l) {
  __builtin_amdgcn_global_load_lds(
      (const __attribute__((address_space(1))) unsigned int*)g,
      (__attribute__((address_space(3))) unsigned int*)l, 16, 0, 0);
}

// ---------------------------------------------------------------- dtype sniff
__global__ void sniff_kernel(const u16* x, int* flag) {
  __shared__ int cnt;
  if (threadIdx.x == 0) cnt = 0;
  __syncthreads();
  int c = 0;
  for (int i = threadIdx.x; i < 4096; i += 256) {
    float a = fabsf(__uint_as_float(((uint32_t)x[2*i]) << 16));
    if (a > 1e-3f && a < 100.f) c++;
  }
  atomicAdd(&cnt, c);
  __syncthreads();
  if (threadIdx.x == 0) *flag = (cnt > 2048) ? 1 : 0;
}

// ------------------------------------------------- 64x64 transpose helper
__device__ __forceinline__ void tr_tile(const void* src, u16* dst, int Kd, int N,
                                        int n0, int k0, int isb, u16* Lt, int tid)
{
  const int r = tid >> 2, cseg = (tid & 3) << 4;
  u16 t[16];
  if (isb) {
    const u16* s = (const u16*)src + (size_t)(k0 + r) * N + n0 + cseg;
    *(uint4*)&t[0] = *(const uint4*)s;
    *(uint4*)&t[8] = *(const uint4*)(s + 8);
  } else {
    const float* s = (const float*)src + (size_t)(k0 + r) * N + n0 + cseg;
    #pragma unroll
    for (int j = 0; j < 4; j++) {
      float4 v = *(const float4*)(s + j * 4);
      t[j*4+0] = f2b(v.x); t[j*4+1] = f2b(v.y); t[j*4+2] = f2b(v.z); t[j*4+3] = f2b(v.w);
    }
  }
  #pragma unroll
  for (int j = 0; j < 16; j++) Lt[(cseg + j) * 72 + r] = t[j];
  __syncthreads();
  const int n = tid >> 2, kseg = (tid & 3) << 4;
  uint4 u0 = *(const uint4*)&Lt[n * 72 + kseg];
  uint4 u1 = *(const uint4*)&Lt[n * 72 + kseg + 8];
  u16* d = dst + (size_t)(n0 + n) * Kd + k0 + kseg;
  *(uint4*)d = u0;
  *(uint4*)(d + 8) = u1;
}

// ------------------------------------------------- fused prep
// blocks [0,2048): x->bf16 ; [2048,2816): Wqkv^T ; [2816,3072): Wout^T ;
// [3072,3328): RoPE table CS[t*32+f] = {cos,sin}
__global__ __launch_bounds__(256) void prep_kernel(
    const void* __restrict__ x, const void* __restrict__ wqkv,
    const void* __restrict__ wout, const int* __restrict__ flag,
    u16* __restrict__ Xb, u16* __restrict__ Wqkvt, u16* __restrict__ Woutt,
    float2* __restrict__ CS)
{
  __shared__ u16 Lt[64 * 72];
  const int isb = *flag;
  const int bid = blockIdx.x, tid = threadIdx.x;
  if (bid < 2048) {
    const size_t i = ((size_t)bid * 256 + tid) * 8;
    if (isb) {
      *(uint4*)&Xb[i] = *(const uint4*)((const u16*)x + i);
    } else {
      const float* s = (const float*)x + i;
      float4 a = *(const float4*)s, b = *(const float4*)(s + 4);
      uint4 p;
      p.x = pkbf(a.x, a.y); p.y = pkbf(a.z, a.w);
      p.z = pkbf(b.x, b.y); p.w = pkbf(b.z, b.w);
      *(uint4*)&Xb[i] = p;
    }
  } else if (bid < 2816) {
    const int b = bid - 2048;
    tr_tile(wqkv, Wqkvt, 1024, 3072, (b % 48) * 64, (b / 48) * 64, isb, Lt, tid);
  } else if (bid < 3072) {
    const int b = bid - 2816;
    tr_tile(wout, Woutt, 1024, 1024, (b % 16) * 64, (b / 16) * 64, isb, Lt, tid);
  } else {
    const int idx = (bid - 3072) * 256 + tid;   // 65536
    const int t = idx >> 5, f = idx & 31;
    float invf = __expf(-(float)f * 0.2878231366242557f);  // ln(1e4)/32
    float th = (float)t * invf;
    float sn, cs;
    sincosf(th, &sn, &cs);
    CS[idx] = make_float2(cs, sn);
  }
}

// ------------------------------------------------- QKV GEMM (NT, bf16) + RoPE
// Q/K waves accumulate C^T (mfma(bf,af)): lane holds 4 consecutive d at fixed
// t -> in-lane RoPE, float4 CS loads, packed uint2 stores. V waves keep the
// original orientation and the sigma-permuted transposed store.
__global__ __launch_bounds__(256) void qkv_kernel(
    const u16* __restrict__ Xb, const u16* __restrict__ Wt,
    const float2* __restrict__ CS,
    u16* __restrict__ Q, u16* __restrict__ K, u16* __restrict__ Vt)
{
  __shared__ u16 As[128 * 64];
  __shared__ u16 Bs[128 * 64];
  const int tid = threadIdx.x;
  const int n0 = blockIdx.x * 128;
  const int m0 = blockIdx.y * 128;
  const int w = tid >> 6, l = tid & 63, lr = l & 15, lq = l >> 4;
  const int mrow0 = (w & 1) * 64;
  const int ncol0 = (w >> 1) * 64;
  const int srow = tid >> 3;
  const int gseg = (tid & 7) ^ (srow & 7);

  const int col0 = n0 + ncol0;
  const int sec = col0 >> 10;            // 0=q 1=k 2=v
  const int isv = (sec == 2);
  const int h = (col0 >> 6) & 15;

  f32x4 acc[4][4] = {};

  for (int k0 = 0; k0 < 1024; k0 += 64) {
    __syncthreads();
    #pragma unroll
    for (int rd = 0; rd < 4; rd++) {
      const int row = srow + rd * 32;
      gl2lds16(Xb + (size_t)(m0 + row) * 1024 + k0 + gseg * 8, &As[tid * 8 + rd * 2048]);
      gl2lds16(Wt + (size_t)(n0 + row) * 1024 + k0 + gseg * 8, &Bs[tid * 8 + rd * 2048]);
    }
    __syncthreads();
    #pragma unroll
    for (int kc = 0; kc < 2; kc++) {
      bf16x8 af[4], bf[4];
      #pragma unroll
      for (int i = 0; i < 4; i++) {
        const int seg = ((kc << 2) | lq) ^ (lr & 7);
        af[i] = *(const bf16x8*)&As[(mrow0 + i * 16 + lr) * 64 + seg * 8];
        bf[i] = *(const bf16x8*)&Bs[(ncol0 + i * 16 + lr) * 64 + seg * 8];
      }
      if (isv) {
        #pragma unroll
        for (int mb = 0; mb < 4; mb++)
          #pragma unroll
          for (int nb = 0; nb < 4; nb++)
            acc[mb][nb] = __builtin_amdgcn_mfma_f32_16x16x32_bf16(af[mb], bf[nb], acc[mb][nb], 0, 0, 0);
      } else {
        // transposed: rows = n (d), cols = m (t)
        #pragma unroll
        for (int mb = 0; mb < 4; mb++)
          #pragma unroll
          for (int nb = 0; nb < 4; nb++)
            acc[mb][nb] = __builtin_amdgcn_mfma_f32_16x16x32_bf16(bf[nb], af[mb], acc[mb][nb], 0, 0, 0);
      }
    }
  }

  if (isv) {
    #pragma unroll
    for (int mb = 0; mb < 4; mb++) {
      const int row0 = m0 + mrow0 + mb * 16 + lq * 4;
      const int b = row0 >> 11, t0 = row0 & 2047;
      // sigma permute within the 32-t block (t0 is a multiple of 4):
      const int tp = (t0 & ~31) | (((t0 >> 2) & 3) << 3) | (((t0 >> 4) & 1) << 2);
      #pragma unroll
      for (int nb = 0; nb < 4; nb++) {
        const int d = nb * 16 + lr;
        uint2 uv;
        uv.x = pkbf(acc[mb][nb][0], acc[mb][nb][1]);
        uv.y = pkbf(acc[mb][nb][2], acc[mb][nb][3]);
        *(uint2*)&Vt[(((size_t)b * 16 + h) * 64 + d) * 2048 + tp] = uv;
      }
    }
  } else {
    u16* dst = (sec == 0) ? Q : K;
    const float qscale = 0.125f * 1.44269504f;   // 1/sqrt(hd) * log2(e), q only
    #pragma unroll
    for (int mb = 0; mb < 4; mb++) {
      const int m = m0 + mrow0 + mb * 16 + lr;   // global row = b*2048 + t
      const int b = m >> 11, t = m & 2047;
      const float* csrow = (const float*)(CS + t * 32);
      #pragma unroll
      for (int nb = 0; nb < 4; nb++) {
        const int d = nb * 16 + lq * 4;          // 4 consecutive d, d%4==0
        const int fb = d & 31;                   // pair block stays within 32
        f32x4 c01 = *(const f32x4*)(csrow + 2 * fb);      // {c0,s0,c1,s1}
        f32x4 c23 = *(const f32x4*)(csrow + 2 * fb + 4);  // {c2,s2,c3,s3}
        float v0 = acc[mb][nb][0], v1 = acc[mb][nb][1];
        float v2 = acc[mb][nb][2], v3 = acc[mb][nb][3];
        float r0 = v0 * c01[0] - v1 * c01[1];
        float r1 = fmaf(v1, c01[2], v0 * c01[3]);
        float r2 = v2 * c23[0] - v3 * c23[1];
        float r3 = fmaf(v3, c23[2], v2 * c23[3]);
        if (sec == 0) { r0 *= qscale; r1 *= qscale; r2 *= qscale; r3 *= qscale; }
        uint2 uv;
        uv.x = pkbf(r0, r1);
        uv.y = pkbf(r2, r3);
        *(uint2*)&dst[(((size_t)b * 16 + h) * 2048 + t) * 64 + d] = uv;
      }
    }
  }
}

// ------------------------------------------------- MFMA flash attention (R7)
// Block = 4 waves x 32 q-rows = 128 rows of one (b,h). grid = 512*ns blocks
// (1D, XCD-bijective swizzle: each XCD owns 4 contiguous bh). Per tile:
// S^T = mfma(Kfrag, Qfrag) -> exp -> in-lane pack (PV k-dim sigma matches the
// sigma-permuted Vt store) -> PV with plain b128 V fragments. Phased body
// (kf and vf never co-live) to fit 4 waves/SIMD.
__global__ __launch_bounds__(256, 4) void attn_kernel(
    const u16* __restrict__ Q, const u16* __restrict__ K,
    const u16* __restrict__ Vt, u16* __restrict__ ATT,
    float* __restrict__ Op, float* __restrict__ Ls, int ns)
{
  __shared__ u16 Ks[2][64 * 64];    // 16 KB
  __shared__ u16 Vs[2][64 * 64];    // 16 KB
  const int tid = threadIdx.x;
  const int w = tid >> 6, l = tid & 63, lr = l & 15, lq = l >> 4;

  // XCD-bijective swizzle: hw block bid runs on XCD bid%8; give each XCD a
  // contiguous chunk of work ids so one XCD sees few distinct (b,h).
  const int nwg = 512 * ns;
  const int bid = blockIdx.x;
  const int swz = (bid & 7) * (nwg >> 3) + (bid >> 3);
  const int per_bh = 16 * ns;
  const int bh = swz / per_bh;
  const int rem = swz - bh * per_bh;
  const int sh = rem & (ns - 1);
  const int qt = rem / ns;

  const int slen = 2048 / ns;
  const int sbeg = sh * slen;
  const size_t base = (size_t)bh * (2048 * 64);
  const int qrow0 = qt * 128 + w * 32;

  // Q fragments (B-operand: col m = lane&15, k = quad*8+j)
  bf16x8 qf[2][2];
  #pragma unroll
  for (int mb = 0; mb < 2; mb++)
    #pragma unroll
    for (int kc = 0; kc < 2; kc++)
      qf[mb][kc] = *(const bf16x8*)(Q + base + (size_t)(qrow0 + mb * 16 + lr) * 64 + kc * 32 + lq * 8);

  f32x4 oa[4][2] = {};            // O^T: [db][mb]
  float lsum[2] = {0.f, 0.f};

  const int srow = tid >> 3;

  auto stage = [&](int buf, int s0) {
    #pragma unroll
    for (int rd = 0; rd < 2; rd++) {
      const int row = srow + rd * 32;
      const int gs = (tid & 7) ^ (row & 7);
      gl2lds16(K + base + (size_t)(s0 + row) * 64 + gs * 8, &Ks[buf][tid * 8 + rd * 2048]);
      gl2lds16(Vt + base + (size_t)row * 2048 + s0 + gs * 8, &Vs[buf][tid * 8 + rd * 2048]);
    }
  };

  stage(0, sbeg);
  const int nt = slen >> 6;

  #pragma unroll 1
  for (int t = 0; t < nt; t++) {
    const int buf = t & 1;
    __syncthreads();                       // drains DMA for buf, fences prev reads
    if (t + 1 < nt) stage(buf ^ 1, sbeg + (t + 1) * 64);

    // ---- S phase: K fragments (A-operand, row s = sb*16+lr, k = kc*32+lq*8+j)
    bf16x8 kf[4][2];
    #pragma unroll
    for (int sb = 0; sb < 4; sb++)
      #pragma unroll
      for (int kc = 0; kc < 2; kc++) {
        const int seg = ((kc << 2) | lq) ^ (lr & 7);
        kf[sb][kc] = *(const bf16x8*)&Ks[buf][(sb * 16 + lr) * 64 + seg * 8];
      }

    uint32_t pw[2][8];
    #pragma unroll
    for (int mb = 0; mb < 2; mb++) {
      f32x4 st[4];
      __builtin_amdgcn_s_setprio(1);
      #pragma unroll
      for (int sb = 0; sb < 4; sb++) {
        f32x4 z = {};
        z = __builtin_amdgcn_mfma_f32_16x16x32_bf16(kf[sb][0], qf[mb][0], z, 0, 0, 0);
        st[sb] = __builtin_amdgcn_mfma_f32_16x16x32_bf16(kf[sb][1], qf[mb][1], z, 0, 0, 0);
      }
      __builtin_amdgcn_s_setprio(0);
      #pragma unroll
      for (int sb = 0; sb < 4; sb++) {
        float e0 = EXP2F(st[sb][0]), e1 = EXP2F(st[sb][1]);
        float e2 = EXP2F(st[sb][2]), e3 = EXP2F(st[sb][3]);
        lsum[mb] += (e0 + e1) + (e2 + e3);
        pw[mb][2 * sb]     = pkbf(e0, e1);
        pw[mb][2 * sb + 1] = pkbf(e2, e3);
      }
    }

    // ---- PV phase: V fragments (A-operand, row d = db*16+lr, sigma-linear k)
    bf16x8 vf[4][2];
    #pragma unroll
    for (int db = 0; db < 4; db++)
      #pragma unroll
      for (int kc = 0; kc < 2; kc++) {
        const int seg = ((kc << 2) | lq) ^ (lr & 7);
        vf[db][kc] = *(const bf16x8*)&Vs[buf][(db * 16 + lr) * 64 + seg * 8];
      }

    __builtin_amdgcn_s_setprio(1);
    #pragma unroll
    for (int mb = 0; mb < 2; mb++) {
      union { uint32_t u[4]; bf16x8 v; } p0, p1;
      p0.u[0] = pw[mb][0]; p0.u[1] = pw[mb][1]; p0.u[2] = pw[mb][2]; p0.u[3] = pw[mb][3];
      p1.u[0] = pw[mb][4]; p1.u[1] = pw[mb][5]; p1.u[2] = pw[mb][6]; p1.u[3] = pw[mb][7];
      #pragma unroll
      for (int db = 0; db < 4; db++) {
        oa[db][mb] = __builtin_amdgcn_mfma_f32_16x16x32_bf16(vf[db][0], p0.v, oa[db][mb], 0, 0, 0);
        oa[db][mb] = __builtin_amdgcn_mfma_f32_16x16x32_bf16(vf[db][1], p1.v, oa[db][mb], 0, 0, 0);
      }
    }
    __builtin_amdgcn_s_setprio(0);
  }

  // reduce row sums across quads (lanes lr, lr+16, lr+32, lr+48)
  #pragma unroll
  for (int mb = 0; mb < 2; mb++) {
    float v = lsum[mb];
    v += __shfl_xor(v, 16, 64);
    v += __shfl_xor(v, 32, 64);
    lsum[mb] = v;
  }

  const int b = bh >> 4, h = bh & 15;
  if (ns == 1) {
    #pragma unroll
    for (int mb = 0; mb < 2; mb++) {
      const float inv = 1.f / lsum[mb];
      const int t = qrow0 + mb * 16 + lr;
      u16* dst = ATT + ((size_t)(b * 2048 + t)) * 1024 + h * 64;
      #pragma unroll
      for (int db = 0; db < 4; db++) {
        uint2 u;
        u.x = pkbf(oa[db][mb][0] * inv, oa[db][mb][1] * inv);
        u.y = pkbf(oa[db][mb][2] * inv, oa[db][mb][3] * inv);
        *(uint2*)&dst[db * 16 + lq * 4] = u;
      }
    }
  } else {
    float* op = Op + (size_t)sh * (65536ull * 64);
    #pragma unroll
    for (int mb = 0; mb < 2; mb++) {
      const size_t row = (size_t)bh * 2048 + qrow0 + mb * 16 + lr;
      #pragma unroll
      for (int db = 0; db < 4; db++)
        *(f32x4*)&op[row * 64 + db * 16 + lq * 4] = oa[db][mb];
      if (lq == 0) Ls[(size_t)sh * 65536 + row] = lsum[mb];
    }
  }
}

// ------------------------------------------------- combine s-split partials
__global__ __launch_bounds__(256) void combine_kernel(
    const float* __restrict__ Op, const float* __restrict__ Ls, u16* __restrict__ ATT)
{
  const int idx = blockIdx.x * 256 + threadIdx.x;   // 524288
  const int R = idx >> 3;
  const int c = (idx & 7) * 8;
  const float* p0 = Op + (size_t)R * 64 + c;
  const float* p1 = p0 + 65536ull * 64;
  f32x4 a0 = *(const f32x4*)p0, a1 = *(const f32x4*)(p0 + 4);
  f32x4 b0 = *(const f32x4*)p1, b1 = *(const f32x4*)(p1 + 4);
  const float inv = 1.f / (Ls[R] + Ls[65536 + R]);
  const int bh = R >> 11, trow = R & 2047;
  const int b = bh >> 4, h = bh & 15;
  u16* d = ATT + ((size_t)(b * 2048 + trow)) * 1024 + h * 64 + c;
  uint4 u;
  u.x = pkbf((a0[0] + b0[0]) * inv, (a0[1] + b0[1]) * inv);
  u.y = pkbf((a0[2] + b0[2]) * inv, (a0[3] + b0[3]) * inv);
  u.z = pkbf((a1[0] + b1[0]) * inv, (a1[1] + b1[1]) * inv);
  u.w = pkbf((a1[2] + b1[2]) * inv, (a1[3] + b1[3]) * inv);
  *(uint4*)d = u;
}

// ------------------------------------------------- output projection (NT, bf16)
// Transposed accumulators throughout: lane holds 4 consecutive cols at fixed
// row -> vector stores (f32x4 or packed uint2).
__global__ __launch_bounds__(256) void outproj_kernel(
    const u16* __restrict__ A, const u16* __restrict__ Wt,
    const int* __restrict__ flag, void* __restrict__ outv)
{
  __shared__ u16 As[128 * 64];
  __shared__ u16 Bs[128 * 64];
  const int isb = *flag;
  const int tid = threadIdx.x;
  const int n0 = blockIdx.x * 128;
  const int m0 = blockIdx.y * 128;
  const int w = tid >> 6, l = tid & 63, lr = l & 15, lq = l >> 4;
  const int mrow0 = (w & 1) * 64;
  const int ncol0 = (w >> 1) * 64;
  const int srow = tid >> 3;
  const int gseg = (tid & 7) ^ (srow & 7);

  f32x4 acc[4][4] = {};

  for (int k0 = 0; k0 < 1024; k0 += 64) {
    __syncthreads();
    #pragma unroll
    for (int rd = 0; rd < 4; rd++) {
      const int row = srow + rd * 32;
      gl2lds16(A + (size_t)(m0 + row) * 1024 + k0 + gseg * 8, &As[tid * 8 + rd * 2048]);
      gl2lds16(Wt + (size_t)(n0 + row) * 1024 + k0 + gseg * 8, &Bs[tid * 8 + rd * 2048]);
    }
    __syncthreads();
    #pragma unroll
    for (int kc = 0; kc < 2; kc++) {
      bf16x8 af[4], bf[4];
      #pragma unroll
      for (int i = 0; i < 4; i++) {
        const int seg = ((kc << 2) | lq) ^ (lr & 7);
        af[i] = *(const bf16x8*)&As[(mrow0 + i * 16 + lr) * 64 + seg * 8];
        bf[i] = *(const bf16x8*)&Bs[(ncol0 + i * 16 + lr) * 64 + seg * 8];
      }
      #pragma unroll
      for (int mb = 0; mb < 4; mb++)
        #pragma unroll
        for (int nb = 0; nb < 4; nb++)
          acc[mb][nb] = __builtin_amdgcn_mfma_f32_16x16x32_bf16(bf[nb], af[mb], acc[mb][nb], 0, 0, 0);
    }
  }
  #pragma unroll
  for (int mb = 0; mb < 4; mb++) {
    const int row = m0 + mrow0 + mb * 16 + lr;
    #pragma unroll
    for (int nb = 0; nb < 4; nb++) {
      const int col = n0 + ncol0 + nb * 16 + lq * 4;
      f32x4 v = acc[mb][nb];
      if (isb) {
        uint2 uv;
        uv.x = pkbf(v[0], v[1]);
        uv.y = pkbf(v[2], v[3]);
        *(uint2*)&((u16*)outv)[(size_t)row * 1024 + col] = uv;
      } else {
        *(f32x4*)&((float*)outv)[(size_t)row * 1024 + col] = v;
      }
    }
  }
}

extern "C" void kernel_launch(void* const* d_in, const int* in_sizes, int n_in,
                              void* d_out, int out_size, void* d_ws, size_t ws_size,
                              hipStream_t stream)
{
  const void* x    = d_in[0];
  const void* wqkv = d_in[1];
  const void* wout = d_in[2];
  char* ws = (char*)d_ws;
  const size_t MB = 1024 * 1024;
  int*    flag   = (int*)ws;
  float2* CS     = (float2*)(ws + 1024);            // 512 KB
  u16*    Xb     = (u16*)(ws + 1 * MB);             // 8 MB  (aliased by ATT)
  u16*    ATT    = Xb;
  u16*    Wqkvt  = (u16*)(ws + 9 * MB);             // 6 MB
  u16*    Woutt  = (u16*)(ws + 15 * MB);            // 2 MB
  u16*    Q      = (u16*)(ws + 17 * MB);            // 8 MB
  u16*    K      = (u16*)(ws + 25 * MB);            // 8 MB
  u16*    Vt     = (u16*)(ws + 33 * MB);            // 8 MB
  float*  Op     = (float*)(ws + 41 * MB);          // 32 MB (ns=2)
  float*  Ls     = (float*)(ws + 75 * MB);          // 0.5 MB

  const bool split = ws_size >= 76 * MB;            // deterministic across calls
  const int ns = split ? 2 : 1;

  sniff_kernel<<<1, 256, 0, stream>>>((const u16*)x, flag);
  prep_kernel<<<3328, 256, 0, stream>>>(x, wqkv, wout, flag, Xb, Wqkvt, Woutt, CS);
  qkv_kernel<<<dim3(24, 32), 256, 0, stream>>>(Xb, Wqkvt, CS, Q, K, Vt);
  attn_kernel<<<dim3(512 * ns), 256, 0, stream>>>(Q, K, Vt, ATT, Op, Ls, ns);
  if (split)
    combine_kernel<<<2048, 256, 0, stream>>>(Op, Ls, ATT);
  outproj_kernel<<<dim3(8, 32), 256, 0, stream>>>(ATT, Woutt, flag, d_out);
}